// Round 8
// baseline (248.941 us; speedup 1.0000x reference)
//
#include <hip/hip_runtime.h>
#include <math.h>

#define N_TOTAL 40960
#define M_EV    4096
#define KNN     32
#define FEAT    192   // CIN + 2*PDIM

__device__ __forceinline__ float dot4f(float4 a, float4 b) {
    return fmaf(a.w, b.w, fmaf(a.z, b.z, fmaf(a.y, b.y, a.x * b.x)));
}

// monotone float->uint key: a<b  <=>  fkey(a)<fkey(b)
__device__ __forceinline__ unsigned fkey(float f) {
    unsigned b = __float_as_uint(f);
    return b ^ ((unsigned)((int)b >> 31) | 0x80000000u);
}

// count of set bits in m at positions below this lane (64-bit mbcnt idiom)
__device__ __forceinline__ int mbcnt64(unsigned long long m) {
    return __builtin_amdgcn_mbcnt_hi((unsigned)(m >> 32),
           __builtin_amdgcn_mbcnt_lo((unsigned)m, 0u));
}

// ---------------------------------------------------------------------------
// Kernel 1: space = x@W_space + b_space  [N,4];  prop = x@W_prop + b_prop [N,64]
// ---------------------------------------------------------------------------
__global__ __launch_bounds__(256) void k_linear(
    const float* __restrict__ x,
    const float* __restrict__ Wp, const float* __restrict__ bp,
    const float* __restrict__ Ws, const float* __restrict__ bs,
    float* __restrict__ prop, float* __restrict__ space)
{
    __shared__ float xs[16 * 64];
    const int t = threadIdx.x;
    const int rowbase = blockIdx.x * 16;

    {
        float4 v = *(const float4*)(x + rowbase * 64 + t * 4);
        *(float4*)(xs + t * 4) = v;
    }
    __syncthreads();

    const int j  = t & 63;
    const int rg = t >> 6;
    float a0 = 0.f, a1 = 0.f, a2 = 0.f, a3 = 0.f;
#pragma unroll 8
    for (int c = 0; c < 64; ++c) {
        float w = Wp[c * 64 + j];
        a0 = fmaf(xs[(rg * 4 + 0) * 64 + c], w, a0);
        a1 = fmaf(xs[(rg * 4 + 1) * 64 + c], w, a1);
        a2 = fmaf(xs[(rg * 4 + 2) * 64 + c], w, a2);
        a3 = fmaf(xs[(rg * 4 + 3) * 64 + c], w, a3);
    }
    const float bj = bp[j];
    prop[(rowbase + rg * 4 + 0) * 64 + j] = a0 + bj;
    prop[(rowbase + rg * 4 + 1) * 64 + j] = a1 + bj;
    prop[(rowbase + rg * 4 + 2) * 64 + j] = a2 + bj;
    prop[(rowbase + rg * 4 + 3) * 64 + j] = a3 + bj;

    if (t < 64) {
        const int r = t >> 2, s = t & 3;
        float a = 0.f;
#pragma unroll 8
        for (int c = 0; c < 64; ++c)
            a = fmaf(xs[r * 64 + c], Ws[c * 4 + s], a);
        space[(rowbase + r) * 4 + s] = a + bs[s];
    }
}

// ---------------------------------------------------------------------------
// Kernel 2: exact kNN, threshold-compact + ballot radix-select.
//  Round 17: REVERT to the round-14 champion (86.0us, VALUBusy 82%,
//  bank-conflict 0; total 225.4) after two failed explorations:
//   - round-15 pass-2 de-staging: 86.0 -> 86.6-87.4 (barriers were
//     already hidden by co-resident waves).
//   - round-16 SoA+packed-FP32 @QPW=4: 102us, VALUBusy 53% (stall-bound;
//     5 LDS reads/cand-pair at half the query amortization). Packed FP32
//     verdict: needs pair-born operands AND >=8q amortization -- mutually
//     exclusive in the VGPR budget. DEAD END, do not retry.
//  Only change vs champion: distance j-loops unroll 2 -> 4 (amortize
//  address/bookkeeping VALU; +~8 VGPR is free, occupancy is grid-limited).
//  Structure: ballot-compaction (cnt in SGPRs), select fast path (cnt<=64),
//  dh = 0.5|c|^2 - q.c staged in s_h, identical fma chain in pass1/pass2/
//  select (exact-compaction invariant), d^2 = 2dh + |q|^2.
// ---------------------------------------------------------------------------
#define QPW   8
#define QPB   32
#define TILEC 1024
#define CCAP  128

__global__ __launch_bounds__(256, 4) void k_knn(
    const float4* __restrict__ space4,
    int* __restrict__ knn_idx, float* __restrict__ knn_w,
    int* __restrict__ bad)
{
    __shared__ float4 s_c[TILEC];         // 16384 B
    __shared__ float  s_h[TILEC];         //  4096 B  (0.5*|c|^2)
    __shared__ ushort s_ci[QPB * CCAP];   //  8192 B  => 28672 B

    const int t = threadIdx.x;
    const int w = t >> 6;                 // wave 0..3
    const int l = t & 63;
    const int qb = blockIdx.x * QPB;
    const int ebase = (qb / M_EV) * M_EV;

    float4 qcs[QPW];                      // plain q
#pragma unroll
    for (int s = 0; s < QPW; ++s)
        qcs[s] = space4[qb + w * QPW + s];

    float mn[QPW];
#pragma unroll
    for (int s = 0; s < QPW; ++s) mn[s] = INFINITY;

    // ---- pass 1: per-lane slice minima of dh (LDS-staged tiles) ----
#pragma unroll 1
    for (int tile = 0; tile < M_EV / TILEC; ++tile) {
        __syncthreads();
#pragma unroll
        for (int u = 0; u < TILEC / 256; ++u) {
            int ci = u * 256 + t;
            float4 c = space4[ebase + tile * TILEC + ci];
            s_c[ci] = c;
            s_h[ci] = 0.5f * dot4f(c, c);
        }
        __syncthreads();
#pragma unroll 4
        for (int j = 0; j < TILEC / 64; ++j) {
            int ci = j * 64 + l;
            float4 c = s_c[ci]; float hc = s_h[ci];
#pragma unroll
            for (int s = 0; s < QPW; ++s) {
                float dh = fmaf(-qcs[s].x, c.x, hc);
                dh = fmaf(-qcs[s].y, c.y, dh);
                dh = fmaf(-qcs[s].z, c.z, dh);
                dh = fmaf(-qcs[s].w, c.w, dh);
                mn[s] = fminf(mn[s], dh);
            }
        }
    }

    // ---- T[s] = 32nd smallest of the 64 lane minima (bitonic, 8q/stage) ----
    float v[QPW];
#pragma unroll
    for (int s = 0; s < QPW; ++s) v[s] = mn[s];
#pragma unroll
    for (int k = 2; k <= 64; k <<= 1) {
#pragma unroll
        for (int j = k >> 1; j >= 1; j >>= 1) {
            bool tmn = (((l & k) == 0) == ((l & j) == 0));
#pragma unroll
            for (int s = 0; s < QPW; ++s) {
                float p = __shfl_xor(v[s], j, 64);
                v[s] = tmn ? fminf(v[s], p) : fmaxf(v[s], p);
            }
        }
    }
    float T[QPW];
#pragma unroll
    for (int s = 0; s < QPW; ++s) T[s] = __shfl(v[s], 31, 64);

    // ---- pass 2: ballot-compact indices with dh<=T (identical fma chain) ----
    int cw[QPW];
#pragma unroll
    for (int s = 0; s < QPW; ++s) cw[s] = 0;

#pragma unroll 1
    for (int tile = 0; tile < M_EV / TILEC; ++tile) {
        __syncthreads();
#pragma unroll
        for (int u = 0; u < TILEC / 256; ++u) {
            int ci = u * 256 + t;
            float4 c = space4[ebase + tile * TILEC + ci];
            s_c[ci] = c;
            s_h[ci] = 0.5f * dot4f(c, c);
        }
        __syncthreads();
#pragma unroll 4
        for (int j = 0; j < TILEC / 64; ++j) {
            int ci = j * 64 + l;
            float4 c = s_c[ci]; float hc = s_h[ci];
#pragma unroll
            for (int s = 0; s < QPW; ++s) {
                float dh = fmaf(-qcs[s].x, c.x, hc);
                dh = fmaf(-qcs[s].y, c.y, dh);
                dh = fmaf(-qcs[s].z, c.z, dh);
                dh = fmaf(-qcs[s].w, c.w, dh);
                bool pass = (dh <= T[s]);
                unsigned long long m = __ballot(pass);
                if (m) {
                    int pos = cw[s] + mbcnt64(m);
                    if (pass && pos < CCAP)
                        s_ci[(w * QPW + s) * CCAP + pos] =
                            (ushort)(tile * TILEC + ci);
                    cw[s] += (int)__popcll(m);
                }
            }
        }
    }
    // own wave wrote its own compact region; DS ops in-order per wave.

    // ---- exact select per query: ballot radix-select ----
#pragma unroll
    for (int s = 0; s < QPW; ++s) {
        const int qi = w * QPW + s;
        const int q  = qb + qi;
        const int cnt = cw[s];                     // wave-uniform
        if (l == 0) bad[q] = (cnt > CCAP) ? 1 : 0;
        if (cnt <= CCAP) {
            const float4 qc = qcs[s];
            const float sqq = dot4f(qc, qc);

            // entry A (slots 0..63)
            const int vA = (l < cnt);
            int iA = vA ? (int)s_ci[qi * CCAP + l] : 0;
            float dA;
            {
                float4 c = space4[ebase + iA];
                float hc = 0.5f * dot4f(c, c);
                float dh = fmaf(-qc.x, c.x, hc);
                dh = fmaf(-qc.y, c.y, dh);
                dh = fmaf(-qc.z, c.z, dh);
                dh = fmaf(-qc.w, c.w, dh);
                dA = dh;
            }
            unsigned uA = vA ? fkey(dA) : 0xFFFFFFFFu;

            unsigned long long sA, sB;
            float dB = 0.f; int iB = 0;

            if (cnt <= 64) {
                // ---- fast path: A only ----
                unsigned kth = 0u;
#pragma unroll
                for (int b = 31; b >= 0; --b) {
                    unsigned cand = kth | (1u << b);
                    int c = __popcll(__ballot(uA < cand));
                    if (c < KNN) kth = cand;
                }
                unsigned long long ltA = __ballot(uA < kth);
                int take = KNN - __popcll(ltA);    // >= 1
                unsigned long long eqA = __ballot(uA == kth);
                if (__popcll(eqA) == take) {
                    sA = ltA | eqA;
                } else {
                    int ki = 0;
#pragma unroll 1
                    for (int b = 12; b >= 0; --b) {
                        int cand = ki | (1 << b);
                        int c = __popcll(__ballot(iA < cand) & eqA);
                        if (c < take) ki = cand;
                    }
                    sA = ltA | (__ballot(iA <= ki) & eqA);
                }
                sB = 0ull;
            } else {
                // ---- full path: A + B ----
                const int vB = (64 + l < cnt);
                iB = vB ? (int)s_ci[qi * CCAP + 64 + l] : 0;
                {
                    float4 c = space4[ebase + iB];
                    float hc = 0.5f * dot4f(c, c);
                    float dh = fmaf(-qc.x, c.x, hc);
                    dh = fmaf(-qc.y, c.y, dh);
                    dh = fmaf(-qc.z, c.z, dh);
                    dh = fmaf(-qc.w, c.w, dh);
                    dB = dh;
                }
                unsigned uB = vB ? fkey(dB) : 0xFFFFFFFFu;

                unsigned kth = 0u;
#pragma unroll
                for (int b = 31; b >= 0; --b) {
                    unsigned cand = kth | (1u << b);
                    int c = __popcll(__ballot(uA < cand))
                          + __popcll(__ballot(uB < cand));
                    if (c < KNN) kth = cand;
                }
                unsigned long long ltA = __ballot(uA < kth);
                unsigned long long ltB = __ballot(uB < kth);
                int take = KNN - (__popcll(ltA) + __popcll(ltB)); // >= 1
                unsigned long long eqA = __ballot(uA == kth);
                unsigned long long eqB = __ballot(uB == kth);
                if (__popcll(eqA) + __popcll(eqB) == take) {
                    sA = ltA | eqA; sB = ltB | eqB;
                } else {
                    int ki = 0;
#pragma unroll 1
                    for (int b = 12; b >= 0; --b) {
                        int cand = ki | (1 << b);
                        int c = __popcll(__ballot(iA < cand) & eqA)
                              + __popcll(__ballot(iB < cand) & eqB);
                        if (c < take) ki = cand;
                    }
                    sA = ltA | (__ballot(iA <= ki) & eqA);
                    sB = ltB | (__ballot(iB <= ki) & eqB);
                }
            }

            // scatter-write: popc(sA)+popc(sB) == 32 exactly
            if ((sA >> l) & 1ull) {
                int pos = mbcnt64(sA);
                float dt = fmaxf(fmaf(2.0f, dA, sqq), 0.0f); // d^2 = 2dh + |q|^2
                knn_idx[q * KNN + pos] = ebase + iA;
                knn_w[q * KNN + pos]   = __expf(-10.0f * dt);
            }
            if ((sB >> l) & 1ull) {
                int pos = __popcll(sA) + mbcnt64(sB);
                float dt = fmaxf(fmaf(2.0f, dB, sqq), 0.0f);
                knn_idx[q * KNN + pos] = ebase + iB;
                knn_w[q * KNN + pos]   = __expf(-10.0f * dt);
            }
        }
    }
}

// ---------------------------------------------------------------------------
// Kernel 2b: exact fallback for flagged queries (expected never to fire).
// ---------------------------------------------------------------------------
__global__ __launch_bounds__(256) void k_fix(
    const float4* __restrict__ space4, const int* __restrict__ bad,
    int* __restrict__ knn_idx, float* __restrict__ knn_w)
{
    const int q = blockIdx.x * 256 + threadIdx.x;
    if (!bad[q]) return;
    const int eb = (q / M_EV) * M_EV;
    float4 qc = space4[q];
    float sqq = dot4f(qc, qc);
    float ld[KNN]; int li[KNN];
    for (int e = 0; e < KNN; ++e) { ld[e] = INFINITY; li[e] = 0; }
    float cm = INFINITY; int mp = 0;
    for (int c = 0; c < M_EV; ++c) {
        float4 cc = space4[eb + c];
        float d = fmaf(-2.0f, dot4f(qc, cc), sqq + dot4f(cc, cc));
        if (d < cm) {
            ld[mp] = d; li[mp] = c;
            cm = ld[0]; mp = 0;
            for (int e = 1; e < KNN; ++e) if (ld[e] > cm) { cm = ld[e]; mp = e; }
        }
    }
    for (int e = 0; e < KNN; ++e) {
        knn_idx[q * KNN + e] = eb + li[e];
        knn_w[q * KNN + e]   = __expf(-10.0f * fmaxf(ld[e], 0.0f));
    }
}

// ---------------------------------------------------------------------------
// Kernel 3 (fused agg+out): round-5 champion form (16-row, FSTR 18).
// Round-6's 32-row re-block regressed ~10us -- do not retry blind.
// ---------------------------------------------------------------------------
#define FSTR 18

__global__ __launch_bounds__(256) void k_tail(
    const float* __restrict__ x, const float* __restrict__ prop,
    const int* __restrict__ knn_idx, const float* __restrict__ knn_w,
    const float* __restrict__ Wo, const float* __restrict__ bo,
    float* __restrict__ out)
{
    __shared__ float fs2[FEAT * FSTR];   // 13824 B
    __shared__ float s_w[48 * 128];      // 24576 B

    const int t = threadIdx.x;
    const int qb = blockIdx.x * 16;

    {
        const int r = t >> 4, c4 = (t & 15) * 4;
        float4 v = *(const float4*)(x + (size_t)(qb + r) * 64 + c4);
        fs2[(c4 + 0) * FSTR + r] = v.x;
        fs2[(c4 + 1) * FSTR + r] = v.y;
        fs2[(c4 + 2) * FSTR + r] = v.z;
        fs2[(c4 + 3) * FSTR + r] = v.w;
    }

    {
        const int p = t & 63;
#pragma unroll 1
        for (int s = 0; s < 4; ++s) {
            const int r = __builtin_amdgcn_readfirstlane(s * 4 + (t >> 6));
            const int q = qb + r;
            float acc = 0.f, mx = -INFINITY;
#pragma unroll 8
            for (int e = 0; e < KNN; ++e) {
                int   ix = knn_idx[q * KNN + e];
                float wv = knn_w[q * KNN + e];
                float g  = wv * prop[(size_t)ix * 64 + p];
                acc += g;
                mx = fmaxf(mx, g);
            }
            fs2[(64 + p) * FSTR + r]  = acc * (1.0f / 32.0f);
            fs2[(128 + p) * FSTR + r] = mx;
        }
    }

    const int rg = t >> 5;
    const int c4 = (t & 31) * 4;
    float acc0[4] = {0.f, 0.f, 0.f, 0.f};
    float acc1[4] = {0.f, 0.f, 0.f, 0.f};

#pragma unroll 1
    for (int cc = 0; cc < 4; ++cc) {
        __syncthreads();
#pragma unroll
        for (int u = 0; u < 6; ++u) {
            int fi = u * 1024 + t * 4;
            *(float4*)(s_w + fi) = *(const float4*)(Wo + (size_t)cc * 48 * 128 + fi);
        }
        __syncthreads();
#pragma unroll 4
        for (int ii = 0; ii < 48; ++ii) {
            int i = cc * 48 + ii;
            float2 f = *(const float2*)(fs2 + i * FSTR + rg * 2);
            float4 wv = *(const float4*)(s_w + ii * 128 + c4);
            acc0[0] = fmaf(f.x, wv.x, acc0[0]); acc0[1] = fmaf(f.x, wv.y, acc0[1]);
            acc0[2] = fmaf(f.x, wv.z, acc0[2]); acc0[3] = fmaf(f.x, wv.w, acc0[3]);
            acc1[0] = fmaf(f.y, wv.x, acc1[0]); acc1[1] = fmaf(f.y, wv.y, acc1[1]);
            acc1[2] = fmaf(f.y, wv.z, acc1[2]); acc1[3] = fmaf(f.y, wv.w, acc1[3]);
        }
    }

    const float4 bc = *(const float4*)(bo + c4);
    float4 o0, o1;
    o0.x = fmaxf(acc0[0] + bc.x, 0.f); o0.y = fmaxf(acc0[1] + bc.y, 0.f);
    o0.z = fmaxf(acc0[2] + bc.z, 0.f); o0.w = fmaxf(acc0[3] + bc.w, 0.f);
    o1.x = fmaxf(acc1[0] + bc.x, 0.f); o1.y = fmaxf(acc1[1] + bc.y, 0.f);
    o1.z = fmaxf(acc1[2] + bc.z, 0.f); o1.w = fmaxf(acc1[3] + bc.w, 0.f);
    *(float4*)(out + (size_t)(qb + rg * 2 + 0) * 128 + c4) = o0;
    *(float4*)(out + (size_t)(qb + rg * 2 + 1) * 128 + c4) = o1;
}

// ---------------------------------------------------------------------------
extern "C" void kernel_launch(void* const* d_in, const int* in_sizes, int n_in,
                              void* d_out, int out_size, void* d_ws, size_t ws_size,
                              hipStream_t stream) {
    const float* x  = (const float*)d_in[0];
    const float* Ws = (const float*)d_in[2];
    const float* bs = (const float*)d_in[3];
    const float* Wp = (const float*)d_in[4];
    const float* bp = (const float*)d_in[5];
    const float* Wo = (const float*)d_in[6];
    const float* bo = (const float*)d_in[7];
    float* out = (float*)d_out;

    float* space = (float*)d_ws;                          // N*4
    float* prop  = space + (size_t)N_TOTAL * 4;           // N*64
    int*   kidx  = (int*)(prop + (size_t)N_TOTAL * 64);   // N*32
    float* kw    = (float*)(kidx + (size_t)N_TOTAL * KNN);// N*32
    int*   bad   = (int*)(kw + (size_t)N_TOTAL * KNN);    // N

    k_linear<<<N_TOTAL / 16, 256, 0, stream>>>(x, Wp, bp, Ws, bs, prop, space);
    k_knn   <<<N_TOTAL / QPB, 256, 0, stream>>>((const float4*)space, kidx, kw, bad);
    k_fix   <<<N_TOTAL / 256, 256, 0, stream>>>((const float4*)space, bad, kidx, kw);
    k_tail  <<<N_TOTAL / 16, 256, 0, stream>>>(x, prop, kidx, kw, Wo, bo, out);
}

// Round 9
// 226.167 us; speedup vs baseline: 1.1007x; 1.1007x over previous
//
#include <hip/hip_runtime.h>
#include <math.h>

#define N_TOTAL 40960
#define M_EV    4096
#define KNN     32
#define FEAT    192   // CIN + 2*PDIM

__device__ __forceinline__ float dot4f(float4 a, float4 b) {
    return fmaf(a.w, b.w, fmaf(a.z, b.z, fmaf(a.y, b.y, a.x * b.x)));
}

// monotone float->uint key: a<b  <=>  fkey(a)<fkey(b)
__device__ __forceinline__ unsigned fkey(float f) {
    unsigned b = __float_as_uint(f);
    return b ^ ((unsigned)((int)b >> 31) | 0x80000000u);
}

// count of set bits in m at positions below this lane (64-bit mbcnt idiom)
__device__ __forceinline__ int mbcnt64(unsigned long long m) {
    return __builtin_amdgcn_mbcnt_hi((unsigned)(m >> 32),
           __builtin_amdgcn_mbcnt_lo((unsigned)m, 0u));
}

// ---------------------------------------------------------------------------
// Kernel 1: space = x@W_space + b_space  [N,4];  prop = x@W_prop + b_prop [N,64]
// ---------------------------------------------------------------------------
__global__ __launch_bounds__(256) void k_linear(
    const float* __restrict__ x,
    const float* __restrict__ Wp, const float* __restrict__ bp,
    const float* __restrict__ Ws, const float* __restrict__ bs,
    float* __restrict__ prop, float* __restrict__ space)
{
    __shared__ float xs[16 * 64];
    const int t = threadIdx.x;
    const int rowbase = blockIdx.x * 16;

    {
        float4 v = *(const float4*)(x + rowbase * 64 + t * 4);
        *(float4*)(xs + t * 4) = v;
    }
    __syncthreads();

    const int j  = t & 63;
    const int rg = t >> 6;
    float a0 = 0.f, a1 = 0.f, a2 = 0.f, a3 = 0.f;
#pragma unroll 8
    for (int c = 0; c < 64; ++c) {
        float w = Wp[c * 64 + j];
        a0 = fmaf(xs[(rg * 4 + 0) * 64 + c], w, a0);
        a1 = fmaf(xs[(rg * 4 + 1) * 64 + c], w, a1);
        a2 = fmaf(xs[(rg * 4 + 2) * 64 + c], w, a2);
        a3 = fmaf(xs[(rg * 4 + 3) * 64 + c], w, a3);
    }
    const float bj = bp[j];
    prop[(rowbase + rg * 4 + 0) * 64 + j] = a0 + bj;
    prop[(rowbase + rg * 4 + 1) * 64 + j] = a1 + bj;
    prop[(rowbase + rg * 4 + 2) * 64 + j] = a2 + bj;
    prop[(rowbase + rg * 4 + 3) * 64 + j] = a3 + bj;

    if (t < 64) {
        const int r = t >> 2, s = t & 3;
        float a = 0.f;
#pragma unroll 8
        for (int c = 0; c < 64; ++c)
            a = fmaf(xs[r * 64 + c], Ws[c * 4 + s], a);
        space[(rowbase + r) * 4 + s] = a + bs[s];
    }
}

// ---------------------------------------------------------------------------
// Kernel 2: exact kNN, threshold-compact + ballot radix-select.
//  Round 18: BYTE-EXACT restore of the round-14 champion (k_knn 86.0us,
//  VALUBusy 82%, bank-conflict 0, VGPR 44; total 225.4us). Post-champion
//  exploration record, all regressions -- do not retry:
//   - pass-2 de-staging (r15): +1us  (barriers already wave-hidden)
//   - SoA + packed FP32 @QPW=4 (r16): +16us (LDS amortization lost;
//     packed needs pair-born operands AND 8q amortization -> VGPR-infeasible)
//   - distance unroll 2->4 (r17): +23us (longer waitcnt dependency runs,
//     occupancy-visible stall collapse; unroll-2 schedule is the optimum)
//  Structure: ballot-compaction (cnt in SGPRs), select fast path (cnt<=64),
//  dh = 0.5|c|^2 - q.c staged in s_h, identical fma chain in pass1/pass2/
//  select (exact-compaction invariant), d^2 = 2dh + |q|^2.
// ---------------------------------------------------------------------------
#define QPW   8
#define QPB   32
#define TILEC 1024
#define CCAP  128

__global__ __launch_bounds__(256, 4) void k_knn(
    const float4* __restrict__ space4,
    int* __restrict__ knn_idx, float* __restrict__ knn_w,
    int* __restrict__ bad)
{
    __shared__ float4 s_c[TILEC];         // 16384 B
    __shared__ float  s_h[TILEC];         //  4096 B  (0.5*|c|^2)
    __shared__ ushort s_ci[QPB * CCAP];   //  8192 B  => 28672 B

    const int t = threadIdx.x;
    const int w = t >> 6;                 // wave 0..3
    const int l = t & 63;
    const int qb = blockIdx.x * QPB;
    const int ebase = (qb / M_EV) * M_EV;

    float4 qcs[QPW];                      // plain q
#pragma unroll
    for (int s = 0; s < QPW; ++s)
        qcs[s] = space4[qb + w * QPW + s];

    float mn[QPW];
#pragma unroll
    for (int s = 0; s < QPW; ++s) mn[s] = INFINITY;

    // ---- pass 1: per-lane slice minima of dh ----
#pragma unroll 1
    for (int tile = 0; tile < M_EV / TILEC; ++tile) {
        __syncthreads();
#pragma unroll
        for (int u = 0; u < TILEC / 256; ++u) {
            int ci = u * 256 + t;
            float4 c = space4[ebase + tile * TILEC + ci];
            s_c[ci] = c;
            s_h[ci] = 0.5f * dot4f(c, c);
        }
        __syncthreads();
#pragma unroll 2
        for (int j = 0; j < TILEC / 64; ++j) {
            int ci = j * 64 + l;
            float4 c = s_c[ci]; float hc = s_h[ci];
#pragma unroll
            for (int s = 0; s < QPW; ++s) {
                float dh = fmaf(-qcs[s].x, c.x, hc);
                dh = fmaf(-qcs[s].y, c.y, dh);
                dh = fmaf(-qcs[s].z, c.z, dh);
                dh = fmaf(-qcs[s].w, c.w, dh);
                mn[s] = fminf(mn[s], dh);
            }
        }
    }

    // ---- T[s] = 32nd smallest of the 64 lane minima (bitonic, 8q/stage) ----
    float v[QPW];
#pragma unroll
    for (int s = 0; s < QPW; ++s) v[s] = mn[s];
#pragma unroll
    for (int k = 2; k <= 64; k <<= 1) {
#pragma unroll
        for (int j = k >> 1; j >= 1; j >>= 1) {
            bool tmn = (((l & k) == 0) == ((l & j) == 0));
#pragma unroll
            for (int s = 0; s < QPW; ++s) {
                float p = __shfl_xor(v[s], j, 64);
                v[s] = tmn ? fminf(v[s], p) : fmaxf(v[s], p);
            }
        }
    }
    float T[QPW];
#pragma unroll
    for (int s = 0; s < QPW; ++s) T[s] = __shfl(v[s], 31, 64);

    // ---- pass 2: ballot-compact indices with dh<=T (identical fma chain) ----
    int cw[QPW];
#pragma unroll
    for (int s = 0; s < QPW; ++s) cw[s] = 0;

#pragma unroll 1
    for (int tile = 0; tile < M_EV / TILEC; ++tile) {
        __syncthreads();
#pragma unroll
        for (int u = 0; u < TILEC / 256; ++u) {
            int ci = u * 256 + t;
            float4 c = space4[ebase + tile * TILEC + ci];
            s_c[ci] = c;
            s_h[ci] = 0.5f * dot4f(c, c);
        }
        __syncthreads();
#pragma unroll 2
        for (int j = 0; j < TILEC / 64; ++j) {
            int ci = j * 64 + l;
            float4 c = s_c[ci]; float hc = s_h[ci];
#pragma unroll
            for (int s = 0; s < QPW; ++s) {
                float dh = fmaf(-qcs[s].x, c.x, hc);
                dh = fmaf(-qcs[s].y, c.y, dh);
                dh = fmaf(-qcs[s].z, c.z, dh);
                dh = fmaf(-qcs[s].w, c.w, dh);
                bool pass = (dh <= T[s]);
                unsigned long long m = __ballot(pass);
                if (m) {
                    int pos = cw[s] + mbcnt64(m);
                    if (pass && pos < CCAP)
                        s_ci[(w * QPW + s) * CCAP + pos] =
                            (ushort)(tile * TILEC + ci);
                    cw[s] += (int)__popcll(m);
                }
            }
        }
    }
    // own wave wrote its own compact region; DS ops in-order per wave.

    // ---- exact select per query: ballot radix-select ----
#pragma unroll
    for (int s = 0; s < QPW; ++s) {
        const int qi = w * QPW + s;
        const int q  = qb + qi;
        const int cnt = cw[s];                     // wave-uniform
        if (l == 0) bad[q] = (cnt > CCAP) ? 1 : 0;
        if (cnt <= CCAP) {
            const float4 qc = qcs[s];
            const float sqq = dot4f(qc, qc);

            // entry A (slots 0..63)
            const int vA = (l < cnt);
            int iA = vA ? (int)s_ci[qi * CCAP + l] : 0;
            float dA;
            {
                float4 c = space4[ebase + iA];
                float hc = 0.5f * dot4f(c, c);
                float dh = fmaf(-qc.x, c.x, hc);
                dh = fmaf(-qc.y, c.y, dh);
                dh = fmaf(-qc.z, c.z, dh);
                dh = fmaf(-qc.w, c.w, dh);
                dA = dh;
            }
            unsigned uA = vA ? fkey(dA) : 0xFFFFFFFFu;

            unsigned long long sA, sB;
            float dB = 0.f; int iB = 0;

            if (cnt <= 64) {
                // ---- fast path: A only ----
                unsigned kth = 0u;
#pragma unroll
                for (int b = 31; b >= 0; --b) {
                    unsigned cand = kth | (1u << b);
                    int c = __popcll(__ballot(uA < cand));
                    if (c < KNN) kth = cand;
                }
                unsigned long long ltA = __ballot(uA < kth);
                int take = KNN - __popcll(ltA);    // >= 1
                unsigned long long eqA = __ballot(uA == kth);
                if (__popcll(eqA) == take) {
                    sA = ltA | eqA;
                } else {
                    int ki = 0;
#pragma unroll 1
                    for (int b = 12; b >= 0; --b) {
                        int cand = ki | (1 << b);
                        int c = __popcll(__ballot(iA < cand) & eqA);
                        if (c < take) ki = cand;
                    }
                    sA = ltA | (__ballot(iA <= ki) & eqA);
                }
                sB = 0ull;
            } else {
                // ---- full path: A + B ----
                const int vB = (64 + l < cnt);
                iB = vB ? (int)s_ci[qi * CCAP + 64 + l] : 0;
                {
                    float4 c = space4[ebase + iB];
                    float hc = 0.5f * dot4f(c, c);
                    float dh = fmaf(-qc.x, c.x, hc);
                    dh = fmaf(-qc.y, c.y, dh);
                    dh = fmaf(-qc.z, c.z, dh);
                    dh = fmaf(-qc.w, c.w, dh);
                    dB = dh;
                }
                unsigned uB = vB ? fkey(dB) : 0xFFFFFFFFu;

                unsigned kth = 0u;
#pragma unroll
                for (int b = 31; b >= 0; --b) {
                    unsigned cand = kth | (1u << b);
                    int c = __popcll(__ballot(uA < cand))
                          + __popcll(__ballot(uB < cand));
                    if (c < KNN) kth = cand;
                }
                unsigned long long ltA = __ballot(uA < kth);
                unsigned long long ltB = __ballot(uB < kth);
                int take = KNN - (__popcll(ltA) + __popcll(ltB)); // >= 1
                unsigned long long eqA = __ballot(uA == kth);
                unsigned long long eqB = __ballot(uB == kth);
                if (__popcll(eqA) + __popcll(eqB) == take) {
                    sA = ltA | eqA; sB = ltB | eqB;
                } else {
                    int ki = 0;
#pragma unroll 1
                    for (int b = 12; b >= 0; --b) {
                        int cand = ki | (1 << b);
                        int c = __popcll(__ballot(iA < cand) & eqA)
                              + __popcll(__ballot(iB < cand) & eqB);
                        if (c < take) ki = cand;
                    }
                    sA = ltA | (__ballot(iA <= ki) & eqA);
                    sB = ltB | (__ballot(iB <= ki) & eqB);
                }
            }

            // scatter-write: popc(sA)+popc(sB) == 32 exactly
            if ((sA >> l) & 1ull) {
                int pos = mbcnt64(sA);
                float dt = fmaxf(fmaf(2.0f, dA, sqq), 0.0f); // d^2 = 2dh + |q|^2
                knn_idx[q * KNN + pos] = ebase + iA;
                knn_w[q * KNN + pos]   = __expf(-10.0f * dt);
            }
            if ((sB >> l) & 1ull) {
                int pos = __popcll(sA) + mbcnt64(sB);
                float dt = fmaxf(fmaf(2.0f, dB, sqq), 0.0f);
                knn_idx[q * KNN + pos] = ebase + iB;
                knn_w[q * KNN + pos]   = __expf(-10.0f * dt);
            }
        }
    }
}

// ---------------------------------------------------------------------------
// Kernel 2b: exact fallback for flagged queries (expected never to fire).
// ---------------------------------------------------------------------------
__global__ __launch_bounds__(256) void k_fix(
    const float4* __restrict__ space4, const int* __restrict__ bad,
    int* __restrict__ knn_idx, float* __restrict__ knn_w)
{
    const int q = blockIdx.x * 256 + threadIdx.x;
    if (!bad[q]) return;
    const int eb = (q / M_EV) * M_EV;
    float4 qc = space4[q];
    float sqq = dot4f(qc, qc);
    float ld[KNN]; int li[KNN];
    for (int e = 0; e < KNN; ++e) { ld[e] = INFINITY; li[e] = 0; }
    float cm = INFINITY; int mp = 0;
    for (int c = 0; c < M_EV; ++c) {
        float4 cc = space4[eb + c];
        float d = fmaf(-2.0f, dot4f(qc, cc), sqq + dot4f(cc, cc));
        if (d < cm) {
            ld[mp] = d; li[mp] = c;
            cm = ld[0]; mp = 0;
            for (int e = 1; e < KNN; ++e) if (ld[e] > cm) { cm = ld[e]; mp = e; }
        }
    }
    for (int e = 0; e < KNN; ++e) {
        knn_idx[q * KNN + e] = eb + li[e];
        knn_w[q * KNN + e]   = __expf(-10.0f * fmaxf(ld[e], 0.0f));
    }
}

// ---------------------------------------------------------------------------
// Kernel 3 (fused agg+out): round-5 champion form (16-row, FSTR 18).
// Round-6's 32-row re-block regressed ~10us -- do not retry blind.
// ---------------------------------------------------------------------------
#define FSTR 18

__global__ __launch_bounds__(256) void k_tail(
    const float* __restrict__ x, const float* __restrict__ prop,
    const int* __restrict__ knn_idx, const float* __restrict__ knn_w,
    const float* __restrict__ Wo, const float* __restrict__ bo,
    float* __restrict__ out)
{
    __shared__ float fs2[FEAT * FSTR];   // 13824 B
    __shared__ float s_w[48 * 128];      // 24576 B

    const int t = threadIdx.x;
    const int qb = blockIdx.x * 16;

    {
        const int r = t >> 4, c4 = (t & 15) * 4;
        float4 v = *(const float4*)(x + (size_t)(qb + r) * 64 + c4);
        fs2[(c4 + 0) * FSTR + r] = v.x;
        fs2[(c4 + 1) * FSTR + r] = v.y;
        fs2[(c4 + 2) * FSTR + r] = v.z;
        fs2[(c4 + 3) * FSTR + r] = v.w;
    }

    {
        const int p = t & 63;
#pragma unroll 1
        for (int s = 0; s < 4; ++s) {
            const int r = __builtin_amdgcn_readfirstlane(s * 4 + (t >> 6));
            const int q = qb + r;
            float acc = 0.f, mx = -INFINITY;
#pragma unroll 8
            for (int e = 0; e < KNN; ++e) {
                int   ix = knn_idx[q * KNN + e];
                float wv = knn_w[q * KNN + e];
                float g  = wv * prop[(size_t)ix * 64 + p];
                acc += g;
                mx = fmaxf(mx, g);
            }
            fs2[(64 + p) * FSTR + r]  = acc * (1.0f / 32.0f);
            fs2[(128 + p) * FSTR + r] = mx;
        }
    }

    const int rg = t >> 5;
    const int c4 = (t & 31) * 4;
    float acc0[4] = {0.f, 0.f, 0.f, 0.f};
    float acc1[4] = {0.f, 0.f, 0.f, 0.f};

#pragma unroll 1
    for (int cc = 0; cc < 4; ++cc) {
        __syncthreads();
#pragma unroll
        for (int u = 0; u < 6; ++u) {
            int fi = u * 1024 + t * 4;
            *(float4*)(s_w + fi) = *(const float4*)(Wo + (size_t)cc * 48 * 128 + fi);
        }
        __syncthreads();
#pragma unroll 4
        for (int ii = 0; ii < 48; ++ii) {
            int i = cc * 48 + ii;
            float2 f = *(const float2*)(fs2 + i * FSTR + rg * 2);
            float4 wv = *(const float4*)(s_w + ii * 128 + c4);
            acc0[0] = fmaf(f.x, wv.x, acc0[0]); acc0[1] = fmaf(f.x, wv.y, acc0[1]);
            acc0[2] = fmaf(f.x, wv.z, acc0[2]); acc0[3] = fmaf(f.x, wv.w, acc0[3]);
            acc1[0] = fmaf(f.y, wv.x, acc1[0]); acc1[1] = fmaf(f.y, wv.y, acc1[1]);
            acc1[2] = fmaf(f.y, wv.z, acc1[2]); acc1[3] = fmaf(f.y, wv.w, acc1[3]);
        }
    }

    const float4 bc = *(const float4*)(bo + c4);
    float4 o0, o1;
    o0.x = fmaxf(acc0[0] + bc.x, 0.f); o0.y = fmaxf(acc0[1] + bc.y, 0.f);
    o0.z = fmaxf(acc0[2] + bc.z, 0.f); o0.w = fmaxf(acc0[3] + bc.w, 0.f);
    o1.x = fmaxf(acc1[0] + bc.x, 0.f); o1.y = fmaxf(acc1[1] + bc.y, 0.f);
    o1.z = fmaxf(acc1[2] + bc.z, 0.f); o1.w = fmaxf(acc1[3] + bc.w, 0.f);
    *(float4*)(out + (size_t)(qb + rg * 2 + 0) * 128 + c4) = o0;
    *(float4*)(out + (size_t)(qb + rg * 2 + 1) * 128 + c4) = o1;
}

// ---------------------------------------------------------------------------
extern "C" void kernel_launch(void* const* d_in, const int* in_sizes, int n_in,
                              void* d_out, int out_size, void* d_ws, size_t ws_size,
                              hipStream_t stream) {
    const float* x  = (const float*)d_in[0];
    const float* Ws = (const float*)d_in[2];
    const float* bs = (const float*)d_in[3];
    const float* Wp = (const float*)d_in[4];
    const float* bp = (const float*)d_in[5];
    const float* Wo = (const float*)d_in[6];
    const float* bo = (const float*)d_in[7];
    float* out = (float*)d_out;

    float* space = (float*)d_ws;                          // N*4
    float* prop  = space + (size_t)N_TOTAL * 4;           // N*64
    int*   kidx  = (int*)(prop + (size_t)N_TOTAL * 64);   // N*32
    float* kw    = (float*)(kidx + (size_t)N_TOTAL * KNN);// N*32
    int*   bad   = (int*)(kw + (size_t)N_TOTAL * KNN);    // N

    k_linear<<<N_TOTAL / 16, 256, 0, stream>>>(x, Wp, bp, Ws, bs, prop, space);
    k_knn   <<<N_TOTAL / QPB, 256, 0, stream>>>((const float4*)space, kidx, kw, bad);
    k_fix   <<<N_TOTAL / 256, 256, 0, stream>>>((const float4*)space, bad, kidx, kw);
    k_tail  <<<N_TOTAL / 16, 256, 0, stream>>>(x, prop, kidx, kw, Wo, bo, out);
}

// Round 10
// 221.800 us; speedup vs baseline: 1.1224x; 1.0197x over previous
//
#include <hip/hip_runtime.h>
#include <math.h>

#define N_TOTAL 40960
#define M_EV    4096
#define KNN     32
#define FEAT    192   // CIN + 2*PDIM

__device__ __forceinline__ float dot4f(float4 a, float4 b) {
    return fmaf(a.w, b.w, fmaf(a.z, b.z, fmaf(a.y, b.y, a.x * b.x)));
}

// monotone float->uint key: a<b  <=>  fkey(a)<fkey(b)
__device__ __forceinline__ unsigned fkey(float f) {
    unsigned b = __float_as_uint(f);
    return b ^ ((unsigned)((int)b >> 31) | 0x80000000u);
}

// count of set bits in m at positions below this lane (64-bit mbcnt idiom)
__device__ __forceinline__ int mbcnt64(unsigned long long m) {
    return __builtin_amdgcn_mbcnt_hi((unsigned)(m >> 32),
           __builtin_amdgcn_mbcnt_lo((unsigned)m, 0u));
}

// ---------------------------------------------------------------------------
// Kernel 1: space = x@W_space + b_space  [N,4];  prop = x@W_prop + b_prop [N,64]
// ---------------------------------------------------------------------------
__global__ __launch_bounds__(256) void k_linear(
    const float* __restrict__ x,
    const float* __restrict__ Wp, const float* __restrict__ bp,
    const float* __restrict__ Ws, const float* __restrict__ bs,
    float* __restrict__ prop, float* __restrict__ space)
{
    __shared__ float xs[16 * 64];
    const int t = threadIdx.x;
    const int rowbase = blockIdx.x * 16;

    {
        float4 v = *(const float4*)(x + rowbase * 64 + t * 4);
        *(float4*)(xs + t * 4) = v;
    }
    __syncthreads();

    const int j  = t & 63;
    const int rg = t >> 6;
    float a0 = 0.f, a1 = 0.f, a2 = 0.f, a3 = 0.f;
#pragma unroll 8
    for (int c = 0; c < 64; ++c) {
        float w = Wp[c * 64 + j];
        a0 = fmaf(xs[(rg * 4 + 0) * 64 + c], w, a0);
        a1 = fmaf(xs[(rg * 4 + 1) * 64 + c], w, a1);
        a2 = fmaf(xs[(rg * 4 + 2) * 64 + c], w, a2);
        a3 = fmaf(xs[(rg * 4 + 3) * 64 + c], w, a3);
    }
    const float bj = bp[j];
    prop[(rowbase + rg * 4 + 0) * 64 + j] = a0 + bj;
    prop[(rowbase + rg * 4 + 1) * 64 + j] = a1 + bj;
    prop[(rowbase + rg * 4 + 2) * 64 + j] = a2 + bj;
    prop[(rowbase + rg * 4 + 3) * 64 + j] = a3 + bj;

    if (t < 64) {
        const int r = t >> 2, s = t & 3;
        float a = 0.f;
#pragma unroll 8
        for (int c = 0; c < 64; ++c)
            a = fmaf(xs[r * 64 + c], Ws[c * 4 + s], a);
        space[(rowbase + r) * 4 + s] = a + bs[s];
    }
}

// ---------------------------------------------------------------------------
// Kernel 2: exact kNN, threshold-compact + ballot radix-select.
//  BYTE-EXACT round-14 champion (k_knn 86.0-86.7us, VALUBusy ~80%,
//  bank-conflict 0, VGPR 44). Exploration record, all regressions --
//  do not retry:
//   - pass-2 de-staging (r15): +1us  (barriers already wave-hidden)
//   - SoA + packed FP32 @QPW=4 (r16): +16us (LDS amortization lost;
//     packed needs pair-born operands AND 8q amortization -> VGPR-infeasible)
//   - distance unroll 2->4 (r17): +23us (longer waitcnt dependency runs;
//     unroll-2 schedule is the optimum)
//  Structure: ballot-compaction (cnt in SGPRs), select fast path (cnt<=64),
//  dh = 0.5|c|^2 - q.c staged in s_h, identical fma chain in pass1/pass2/
//  select (exact-compaction invariant), d^2 = 2dh + |q|^2.
// ---------------------------------------------------------------------------
#define QPW   8
#define QPB   32
#define TILEC 1024
#define CCAP  128

__global__ __launch_bounds__(256, 4) void k_knn(
    const float4* __restrict__ space4,
    int* __restrict__ knn_idx, float* __restrict__ knn_w,
    int* __restrict__ bad)
{
    __shared__ float4 s_c[TILEC];         // 16384 B
    __shared__ float  s_h[TILEC];         //  4096 B  (0.5*|c|^2)
    __shared__ ushort s_ci[QPB * CCAP];   //  8192 B  => 28672 B

    const int t = threadIdx.x;
    const int w = t >> 6;                 // wave 0..3
    const int l = t & 63;
    const int qb = blockIdx.x * QPB;
    const int ebase = (qb / M_EV) * M_EV;

    float4 qcs[QPW];                      // plain q
#pragma unroll
    for (int s = 0; s < QPW; ++s)
        qcs[s] = space4[qb + w * QPW + s];

    float mn[QPW];
#pragma unroll
    for (int s = 0; s < QPW; ++s) mn[s] = INFINITY;

    // ---- pass 1: per-lane slice minima of dh ----
#pragma unroll 1
    for (int tile = 0; tile < M_EV / TILEC; ++tile) {
        __syncthreads();
#pragma unroll
        for (int u = 0; u < TILEC / 256; ++u) {
            int ci = u * 256 + t;
            float4 c = space4[ebase + tile * TILEC + ci];
            s_c[ci] = c;
            s_h[ci] = 0.5f * dot4f(c, c);
        }
        __syncthreads();
#pragma unroll 2
        for (int j = 0; j < TILEC / 64; ++j) {
            int ci = j * 64 + l;
            float4 c = s_c[ci]; float hc = s_h[ci];
#pragma unroll
            for (int s = 0; s < QPW; ++s) {
                float dh = fmaf(-qcs[s].x, c.x, hc);
                dh = fmaf(-qcs[s].y, c.y, dh);
                dh = fmaf(-qcs[s].z, c.z, dh);
                dh = fmaf(-qcs[s].w, c.w, dh);
                mn[s] = fminf(mn[s], dh);
            }
        }
    }

    // ---- T[s] = 32nd smallest of the 64 lane minima (bitonic, 8q/stage) ----
    float v[QPW];
#pragma unroll
    for (int s = 0; s < QPW; ++s) v[s] = mn[s];
#pragma unroll
    for (int k = 2; k <= 64; k <<= 1) {
#pragma unroll
        for (int j = k >> 1; j >= 1; j >>= 1) {
            bool tmn = (((l & k) == 0) == ((l & j) == 0));
#pragma unroll
            for (int s = 0; s < QPW; ++s) {
                float p = __shfl_xor(v[s], j, 64);
                v[s] = tmn ? fminf(v[s], p) : fmaxf(v[s], p);
            }
        }
    }
    float T[QPW];
#pragma unroll
    for (int s = 0; s < QPW; ++s) T[s] = __shfl(v[s], 31, 64);

    // ---- pass 2: ballot-compact indices with dh<=T (identical fma chain) ----
    int cw[QPW];
#pragma unroll
    for (int s = 0; s < QPW; ++s) cw[s] = 0;

#pragma unroll 1
    for (int tile = 0; tile < M_EV / TILEC; ++tile) {
        __syncthreads();
#pragma unroll
        for (int u = 0; u < TILEC / 256; ++u) {
            int ci = u * 256 + t;
            float4 c = space4[ebase + tile * TILEC + ci];
            s_c[ci] = c;
            s_h[ci] = 0.5f * dot4f(c, c);
        }
        __syncthreads();
#pragma unroll 2
        for (int j = 0; j < TILEC / 64; ++j) {
            int ci = j * 64 + l;
            float4 c = s_c[ci]; float hc = s_h[ci];
#pragma unroll
            for (int s = 0; s < QPW; ++s) {
                float dh = fmaf(-qcs[s].x, c.x, hc);
                dh = fmaf(-qcs[s].y, c.y, dh);
                dh = fmaf(-qcs[s].z, c.z, dh);
                dh = fmaf(-qcs[s].w, c.w, dh);
                bool pass = (dh <= T[s]);
                unsigned long long m = __ballot(pass);
                if (m) {
                    int pos = cw[s] + mbcnt64(m);
                    if (pass && pos < CCAP)
                        s_ci[(w * QPW + s) * CCAP + pos] =
                            (ushort)(tile * TILEC + ci);
                    cw[s] += (int)__popcll(m);
                }
            }
        }
    }
    // own wave wrote its own compact region; DS ops in-order per wave.

    // ---- exact select per query: ballot radix-select ----
#pragma unroll
    for (int s = 0; s < QPW; ++s) {
        const int qi = w * QPW + s;
        const int q  = qb + qi;
        const int cnt = cw[s];                     // wave-uniform
        if (l == 0) bad[q] = (cnt > CCAP) ? 1 : 0;
        if (cnt <= CCAP) {
            const float4 qc = qcs[s];
            const float sqq = dot4f(qc, qc);

            // entry A (slots 0..63)
            const int vA = (l < cnt);
            int iA = vA ? (int)s_ci[qi * CCAP + l] : 0;
            float dA;
            {
                float4 c = space4[ebase + iA];
                float hc = 0.5f * dot4f(c, c);
                float dh = fmaf(-qc.x, c.x, hc);
                dh = fmaf(-qc.y, c.y, dh);
                dh = fmaf(-qc.z, c.z, dh);
                dh = fmaf(-qc.w, c.w, dh);
                dA = dh;
            }
            unsigned uA = vA ? fkey(dA) : 0xFFFFFFFFu;

            unsigned long long sA, sB;
            float dB = 0.f; int iB = 0;

            if (cnt <= 64) {
                // ---- fast path: A only ----
                unsigned kth = 0u;
#pragma unroll
                for (int b = 31; b >= 0; --b) {
                    unsigned cand = kth | (1u << b);
                    int c = __popcll(__ballot(uA < cand));
                    if (c < KNN) kth = cand;
                }
                unsigned long long ltA = __ballot(uA < kth);
                int take = KNN - __popcll(ltA);    // >= 1
                unsigned long long eqA = __ballot(uA == kth);
                if (__popcll(eqA) == take) {
                    sA = ltA | eqA;
                } else {
                    int ki = 0;
#pragma unroll 1
                    for (int b = 12; b >= 0; --b) {
                        int cand = ki | (1 << b);
                        int c = __popcll(__ballot(iA < cand) & eqA);
                        if (c < take) ki = cand;
                    }
                    sA = ltA | (__ballot(iA <= ki) & eqA);
                }
                sB = 0ull;
            } else {
                // ---- full path: A + B ----
                const int vB = (64 + l < cnt);
                iB = vB ? (int)s_ci[qi * CCAP + 64 + l] : 0;
                {
                    float4 c = space4[ebase + iB];
                    float hc = 0.5f * dot4f(c, c);
                    float dh = fmaf(-qc.x, c.x, hc);
                    dh = fmaf(-qc.y, c.y, dh);
                    dh = fmaf(-qc.z, c.z, dh);
                    dh = fmaf(-qc.w, c.w, dh);
                    dB = dh;
                }
                unsigned uB = vB ? fkey(dB) : 0xFFFFFFFFu;

                unsigned kth = 0u;
#pragma unroll
                for (int b = 31; b >= 0; --b) {
                    unsigned cand = kth | (1u << b);
                    int c = __popcll(__ballot(uA < cand))
                          + __popcll(__ballot(uB < cand));
                    if (c < KNN) kth = cand;
                }
                unsigned long long ltA = __ballot(uA < kth);
                unsigned long long ltB = __ballot(uB < kth);
                int take = KNN - (__popcll(ltA) + __popcll(ltB)); // >= 1
                unsigned long long eqA = __ballot(uA == kth);
                unsigned long long eqB = __ballot(uB == kth);
                if (__popcll(eqA) + __popcll(eqB) == take) {
                    sA = ltA | eqA; sB = ltB | eqB;
                } else {
                    int ki = 0;
#pragma unroll 1
                    for (int b = 12; b >= 0; --b) {
                        int cand = ki | (1 << b);
                        int c = __popcll(__ballot(iA < cand) & eqA)
                              + __popcll(__ballot(iB < cand) & eqB);
                        if (c < take) ki = cand;
                    }
                    sA = ltA | (__ballot(iA <= ki) & eqA);
                    sB = ltB | (__ballot(iB <= ki) & eqB);
                }
            }

            // scatter-write: popc(sA)+popc(sB) == 32 exactly
            if ((sA >> l) & 1ull) {
                int pos = mbcnt64(sA);
                float dt = fmaxf(fmaf(2.0f, dA, sqq), 0.0f); // d^2 = 2dh + |q|^2
                knn_idx[q * KNN + pos] = ebase + iA;
                knn_w[q * KNN + pos]   = __expf(-10.0f * dt);
            }
            if ((sB >> l) & 1ull) {
                int pos = __popcll(sA) + mbcnt64(sB);
                float dt = fmaxf(fmaf(2.0f, dB, sqq), 0.0f);
                knn_idx[q * KNN + pos] = ebase + iB;
                knn_w[q * KNN + pos]   = __expf(-10.0f * dt);
            }
        }
    }
}

// ---------------------------------------------------------------------------
// Kernel 2b: exact fallback for flagged queries (expected never to fire).
// ---------------------------------------------------------------------------
__global__ __launch_bounds__(256) void k_fix(
    const float4* __restrict__ space4, const int* __restrict__ bad,
    int* __restrict__ knn_idx, float* __restrict__ knn_w)
{
    const int q = blockIdx.x * 256 + threadIdx.x;
    if (!bad[q]) return;
    const int eb = (q / M_EV) * M_EV;
    float4 qc = space4[q];
    float sqq = dot4f(qc, qc);
    float ld[KNN]; int li[KNN];
    for (int e = 0; e < KNN; ++e) { ld[e] = INFINITY; li[e] = 0; }
    float cm = INFINITY; int mp = 0;
    for (int c = 0; c < M_EV; ++c) {
        float4 cc = space4[eb + c];
        float d = fmaf(-2.0f, dot4f(qc, cc), sqq + dot4f(cc, cc));
        if (d < cm) {
            ld[mp] = d; li[mp] = c;
            cm = ld[0]; mp = 0;
            for (int e = 1; e < KNN; ++e) if (ld[e] > cm) { cm = ld[e]; mp = e; }
        }
    }
    for (int e = 0; e < KNN; ++e) {
        knn_idx[q * KNN + e] = eb + li[e];
        knn_w[q * KNN + e]   = __expf(-10.0f * fmaxf(ld[e], 0.0f));
    }
}

// ---------------------------------------------------------------------------
// Kernel 3 (fused agg+out).
//  Round 19: phase C only -- split-ii 4r x 4c per-thread tile.
//   * Theory: phase C was the largest non-knn term; LDS traffic/block was
//     256 thr x 192 i x 24 B = 1.18 MB (2r4c = 24 B per 8 fma). New
//     mapping: half = t>>7 processes ii 0..23 vs 24..47 of the SAME live
//     s_w chunk; each thread 4 rows x 4 cols = 32 B per 16 fma -> 786 KB
//     (-33%). VALU floor unchanged (~25us); LDS pole shrinks.
//   * Phase A, phase B, FSTR=18, 16-row tile, 4 cc chunks, s_w staging,
//     and barrier structure are BYTE-IDENTICAL to the champion (round-6's
//     regression bundled tile/barrier changes; this isolates the mapping).
//   * Cross-half reduction once per block via s_w (stride 20: b128-aligned,
//     ~8-way bank bounded, 2 extra barriers per block total). Summation
//     order becomes (first-half sum)+(second-half sum): ulp-level change.
// ---------------------------------------------------------------------------
#define FSTR 18

__global__ __launch_bounds__(256) void k_tail(
    const float* __restrict__ x, const float* __restrict__ prop,
    const int* __restrict__ knn_idx, const float* __restrict__ knn_w,
    const float* __restrict__ Wo, const float* __restrict__ bo,
    float* __restrict__ out)
{
    __shared__ float fs2[FEAT * FSTR];   // 13824 B
    __shared__ float s_w[48 * 128];      // 24576 B

    const int t = threadIdx.x;
    const int qb = blockIdx.x * 16;

    {
        const int r = t >> 4, c4 = (t & 15) * 4;
        float4 v = *(const float4*)(x + (size_t)(qb + r) * 64 + c4);
        fs2[(c4 + 0) * FSTR + r] = v.x;
        fs2[(c4 + 1) * FSTR + r] = v.y;
        fs2[(c4 + 2) * FSTR + r] = v.z;
        fs2[(c4 + 3) * FSTR + r] = v.w;
    }

    {
        const int p = t & 63;
#pragma unroll 1
        for (int s = 0; s < 4; ++s) {
            const int r = __builtin_amdgcn_readfirstlane(s * 4 + (t >> 6));
            const int q = qb + r;
            float acc = 0.f, mx = -INFINITY;
#pragma unroll 8
            for (int e = 0; e < KNN; ++e) {
                int   ix = knn_idx[q * KNN + e];
                float wv = knn_w[q * KNN + e];
                float g  = wv * prop[(size_t)ix * 64 + p];
                acc += g;
                mx = fmaxf(mx, g);
            }
            fs2[(64 + p) * FSTR + r]  = acc * (1.0f / 32.0f);
            fs2[(128 + p) * FSTR + r] = mx;
        }
    }

    // ---- phase C: [16x192] @ [192x128]; 4r x 4c per thread, split-ii ----
    const int half = t >> 7;             // 0: ii 0..23, 1: ii 24..47
    const int rq   = (t >> 5) & 3;       // row quad: rows rq*4..rq*4+3
    const int cq4  = (t & 31) * 4;       // col base
    float4 a0 = {0.f,0.f,0.f,0.f}, a1 = {0.f,0.f,0.f,0.f};
    float4 a2 = {0.f,0.f,0.f,0.f}, a3 = {0.f,0.f,0.f,0.f};

#pragma unroll 1
    for (int cc = 0; cc < 4; ++cc) {
        __syncthreads();
#pragma unroll
        for (int u = 0; u < 6; ++u) {
            int fi = u * 1024 + t * 4;
            *(float4*)(s_w + fi) = *(const float4*)(Wo + (size_t)cc * 48 * 128 + fi);
        }
        __syncthreads();
#pragma unroll 4
        for (int jj = 0; jj < 24; ++jj) {
            int iiL = half * 24 + jj;            // s_w-local row
            int i   = cc * 48 + iiL;             // fs2 row
            float2 fA = *(const float2*)(fs2 + i * FSTR + rq * 4);
            float2 fB = *(const float2*)(fs2 + i * FSTR + rq * 4 + 2);
            float4 wv = *(const float4*)(s_w + iiL * 128 + cq4);
            a0.x = fmaf(fA.x, wv.x, a0.x); a0.y = fmaf(fA.x, wv.y, a0.y);
            a0.z = fmaf(fA.x, wv.z, a0.z); a0.w = fmaf(fA.x, wv.w, a0.w);
            a1.x = fmaf(fA.y, wv.x, a1.x); a1.y = fmaf(fA.y, wv.y, a1.y);
            a1.z = fmaf(fA.y, wv.z, a1.z); a1.w = fmaf(fA.y, wv.w, a1.w);
            a2.x = fmaf(fB.x, wv.x, a2.x); a2.y = fmaf(fB.x, wv.y, a2.y);
            a2.z = fmaf(fB.x, wv.z, a2.z); a2.w = fmaf(fB.x, wv.w, a2.w);
            a3.x = fmaf(fB.y, wv.x, a3.x); a3.y = fmaf(fB.y, wv.y, a3.y);
            a3.z = fmaf(fB.y, wv.z, a3.z); a3.w = fmaf(fB.y, wv.w, a3.w);
        }
    }

    // ---- cross-half reduce via s_w (stride 20: aligned, conflict-bounded) ----
    __syncthreads();
    if (half) {
        float* p = s_w + (t & 127) * 20;
        *(float4*)(p + 0)  = a0;
        *(float4*)(p + 4)  = a1;
        *(float4*)(p + 8)  = a2;
        *(float4*)(p + 12) = a3;
    }
    __syncthreads();
    if (!half) {
        const float* p = s_w + t * 20;
        float4 b0 = *(const float4*)(p + 0);
        float4 b1 = *(const float4*)(p + 4);
        float4 b2 = *(const float4*)(p + 8);
        float4 b3 = *(const float4*)(p + 12);
        const float4 bc = *(const float4*)(bo + cq4);
        float4 o0, o1, o2, o3;
        o0.x = fmaxf(a0.x + b0.x + bc.x, 0.f); o0.y = fmaxf(a0.y + b0.y + bc.y, 0.f);
        o0.z = fmaxf(a0.z + b0.z + bc.z, 0.f); o0.w = fmaxf(a0.w + b0.w + bc.w, 0.f);
        o1.x = fmaxf(a1.x + b1.x + bc.x, 0.f); o1.y = fmaxf(a1.y + b1.y + bc.y, 0.f);
        o1.z = fmaxf(a1.z + b1.z + bc.z, 0.f); o1.w = fmaxf(a1.w + b1.w + bc.w, 0.f);
        o2.x = fmaxf(a2.x + b2.x + bc.x, 0.f); o2.y = fmaxf(a2.y + b2.y + bc.y, 0.f);
        o2.z = fmaxf(a2.z + b2.z + bc.z, 0.f); o2.w = fmaxf(a2.w + b2.w + bc.w, 0.f);
        o3.x = fmaxf(a3.x + b3.x + bc.x, 0.f); o3.y = fmaxf(a3.y + b3.y + bc.y, 0.f);
        o3.z = fmaxf(a3.z + b3.z + bc.z, 0.f); o3.w = fmaxf(a3.w + b3.w + bc.w, 0.f);
        *(float4*)(out + (size_t)(qb + rq * 4 + 0) * 128 + cq4) = o0;
        *(float4*)(out + (size_t)(qb + rq * 4 + 1) * 128 + cq4) = o1;
        *(float4*)(out + (size_t)(qb + rq * 4 + 2) * 128 + cq4) = o2;
        *(float4*)(out + (size_t)(qb + rq * 4 + 3) * 128 + cq4) = o3;
    }
}

// ---------------------------------------------------------------------------
extern "C" void kernel_launch(void* const* d_in, const int* in_sizes, int n_in,
                              void* d_out, int out_size, void* d_ws, size_t ws_size,
                              hipStream_t stream) {
    const float* x  = (const float*)d_in[0];
    const float* Ws = (const float*)d_in[2];
    const float* bs = (const float*)d_in[3];
    const float* Wp = (const float*)d_in[4];
    const float* bp = (const float*)d_in[5];
    const float* Wo = (const float*)d_in[6];
    const float* bo = (const float*)d_in[7];
    float* out = (float*)d_out;

    float* space = (float*)d_ws;                          // N*4
    float* prop  = space + (size_t)N_TOTAL * 4;           // N*64
    int*   kidx  = (int*)(prop + (size_t)N_TOTAL * 64);   // N*32
    float* kw    = (float*)(kidx + (size_t)N_TOTAL * KNN);// N*32
    int*   bad   = (int*)(kw + (size_t)N_TOTAL * KNN);    // N

    k_linear<<<N_TOTAL / 16, 256, 0, stream>>>(x, Wp, bp, Ws, bs, prop, space);
    k_knn   <<<N_TOTAL / QPB, 256, 0, stream>>>((const float4*)space, kidx, kw, bad);
    k_fix   <<<N_TOTAL / 256, 256, 0, stream>>>((const float4*)space, bad, kidx, kw);
    k_tail  <<<N_TOTAL / 16, 256, 0, stream>>>(x, prop, kidx, kw, Wo, bo, out);
}